// Round 10
// baseline (304.769 us; speedup 1.0000x reference)
//
#include <hip/hip_runtime.h>

#define HW  (512*512)

typedef _Float16 half8  __attribute__((__vector_size__(16)));
typedef _Float16 half4  __attribute__((__vector_size__(8)));
typedef _Float16 half2_t __attribute__((__vector_size__(4)));
typedef float    floatx4 __attribute__((__vector_size__(16)));

__device__ __forceinline__ float gelu_f(float x){
    float x2 = x * x;
    float q  = __builtin_fmaf(x2, -0.1029432f, -2.3022079f);
    float e  = __builtin_amdgcn_exp2f(x * q);
    return x * __builtin_amdgcn_rcpf(1.0f + e);
}

__device__ __forceinline__ float sigmoid_f(float x){
    float e = __builtin_amdgcn_exp2f(-1.44269504f * x);
    return __builtin_amdgcn_rcpf(1.0f + e);
}

// act layout (per 32-px sub-tile): element (px, n) at f16 offset
// px*256 + ((n>>3) ^ (px&7))*8 + (n&7)  — proven bank-clean in R9.

// ---------------- prep: coalesced weight pack + per-batch c0 (unchanged R9) ----
__global__ void prep_all(const float* __restrict__ W1, const float* __restrict__ W2,
                         const float* __restrict__ W3, const float* __restrict__ emb,
                         const int* __restrict__ sidx, const float* __restrict__ W0,
                         const float* __restrict__ b0,
                         _Float16* __restrict__ wp, float* __restrict__ c0){
    __shared__ float ld[32][68];
    int blk = blockIdx.x;
    int tid = threadIdx.x;
    if (blk < 64){
        int mat = blk >> 5;
        int g   = blk & 31;
        int ks  = g >> 2;
        int ntq = g & 3;
        const float* W = mat ? W2 : W1;
        int row = tid >> 3;
        int c8  = (tid & 7) * 8;
        const float* src = &W[(ks*32 + row)*256 + ntq*64 + c8];
        *(floatx4*)&ld[row][c8]     = *(const floatx4*)src;
        *(floatx4*)&ld[row][c8 + 4] = *(const floatx4*)(src + 4);
        __syncthreads();
        int lane = tid & 63;
        int nt_l = tid >> 6;
        half8 h;
        #pragma unroll
        for (int j = 0; j < 8; j++)
            h[j] = (_Float16)ld[(lane >> 4)*8 + j][nt_l*16 + (lane & 15)];
        _Float16* dst = wp + mat*65536 + (ks*16 + ntq*4 + nt_l)*512 + lane*8;
        *(half8*)dst = h;
    } else if (blk < 80){
        int i    = (blk - 64)*256 + tid;
        int j    = i & 7;
        int lane = (i >> 3) & 63;
        int ks   = i >> 9;
        int k = ks*32 + ((lane >> 4) << 3) + j;
        int n = lane & 15;
        wp[131072 + i] = (_Float16)((n < 3) ? W3[k*3 + n] : 0.0f);
    } else {
        int b = blk - 80;
        int s = sidx[b];
        float acc = b0[tid];
        #pragma unroll 8
        for (int d = 0; d < 64; d++)
            acc = fmaf(emb[s*64 + d], W0[(3 + d)*256 + tid], acc);
        c0[b*256 + tid] = acc;
    }
}

struct Acc { floatx4 a[2][4]; };

__device__ __forceinline__ floatx4 mfma16(half8 a, half8 b, floatx4 c){
    return __builtin_amdgcn_mfma_f32_16x16x32_f16(a, b, c, 0, 0, 0);
}

// ---------------- fused MLP: 64-px tile split into two 32-px streams ----------
__global__ __launch_bounds__(256, 4)
void nilut_main(const float* __restrict__ rgb,
                const float* __restrict__ W0,
                const float* __restrict__ b1v,
                const float* __restrict__ b2v,
                const float* __restrict__ b3v,
                const _Float16* __restrict__ wp,
                const float* __restrict__ c0,
                float* __restrict__ out){
    __shared__ __align__(16) _Float16 act[2][32 * 256];  // 2 x 16384 B
    __shared__ __align__(16) float    w0s[1024];         // W0|c0; later out bounce
    __shared__ __align__(16) float    rgbs[192];         // rgb tile [3][64]

    const int tid = threadIdx.x;
    const int wg  = blockIdx.x;
    const int pixbase = wg * 64;
    const int b   = pixbase >> 18;
    const int hw0 = pixbase & (HW - 1);

    // ---- stage ----
    #pragma unroll
    for (int r = 0; r < 4; r++){
        int q = r*256 + tid;
        w0s[q] = (q < 768) ? W0[q] : c0[b*256 + (q - 768)];
    }
    if (tid < 192){
        int c = tid >> 6, row = tid & 63;
        rgbs[tid] = rgb[b*3*HW + c*HW + hw0 + row];
    }
    __syncthreads();

    const int lane = tid & 63;
    const int wv   = tid >> 6;
    const int ln15 = lane & 15;
    const int quad = lane >> 4;
    const int qr   = quad * 4;
    const int sx   = ln15 & 7;
    const int qx8  = (quad ^ (sx & 3)) * 8;
    const int kb32 = ((sx >> 2) & 1) << 5;
    const int qh   = quad >> 1, qs = (quad & 1) * 4;
    const int pb0  = ln15*256 + qx8,  pb1 = (16 + ln15)*256 + qx8;
    const int eb0  = ln15*256 + qs,   eb1 = (16 + ln15)*256 + qs;
    const int ng   = tid & 31, rg = tid >> 5;

    const half8* wp1 = (const half8*)wp;
    const half8* wp2 = (const half8*)(wp + 65536);
    const half8* wp3 = (const half8*)(wp + 131072);

    // layer-0 coeffs in registers (live S1-S2 only)
    floatx4 cw[4][2];
    #pragma unroll
    for (int p = 0; p < 4; p++){
        cw[p][0] = *(const floatx4*)&w0s[p*256 + ng*8];
        cw[p][1] = *(const floatx4*)&w0s[p*256 + ng*8 + 4];
    }

    Acc accA, accB;
    floatx4 accfA = (floatx4){0.f,0.f,0.f,0.f};
    floatx4 accfB = (floatx4){0.f,0.f,0.f,0.f};

    // ---------------- phase helpers (inline lambdas) ----------------
    auto L0 = [&](int s){
        floatx4 rv[3];
        #pragma unroll
        for (int c = 0; c < 3; c++)
            rv[c] = *(const floatx4*)&rgbs[c*64 + s*32 + rg*4];
        #pragma unroll
        for (int r4 = 0; r4 < 4; r4++){
            int px = rg*4 + r4;
            float rr = rv[0][r4], gg = rv[1][r4], bb = rv[2][r4];
            half8 v;
            #pragma unroll
            for (int j = 0; j < 8; j++){
                int hi = j >> 2, lo = j & 3;
                float z = fmaf(rr, cw[0][hi][lo],
                          fmaf(gg, cw[1][hi][lo],
                          fmaf(bb, cw[2][hi][lo], cw[3][hi][lo])));
                v[j] = (_Float16)gelu_f(z);
            }
            *(half8*)&act[s][px*256 + ((ng ^ (px & 7)) << 3)] = v;
        }
    };

    auto KL = [&](int s, const half8* w8, const float* bias, Acc& A){
        #pragma unroll
        for (int mtl = 0; mtl < 4; mtl++){
            floatx4 bv = *(const floatx4*)&bias[(wv*4 + mtl)*16 + qr];
            A.a[0][mtl] = bv; A.a[1][mtl] = bv;
        }
        #pragma unroll 2
        for (int ks = 0; ks < 8; ks++){
            int t = (ks << 5) ^ kb32;
            half8 bf0 = *(const half8*)&act[s][pb0 + t];
            half8 bf1 = *(const half8*)&act[s][pb1 + t];
            #pragma unroll
            for (int mtl = 0; mtl < 4; mtl++){
                half8 af = w8[(ks*16 + wv*4 + mtl)*64 + lane];
                A.a[0][mtl] = mfma16(af, bf0, A.a[0][mtl]);
                A.a[1][mtl] = mfma16(af, bf1, A.a[1][mtl]);
            }
        }
    };

    auto EP = [&](int s, Acc& A){
        #pragma unroll
        for (int mtl = 0; mtl < 4; mtl++){
            int cx = (((wv*4 + mtl)*2 + qh) ^ sx) << 3;
            #pragma unroll
            for (int pt = 0; pt < 2; pt++){
                floatx4 v = A.a[pt][mtl];
                half2_t g01 = __builtin_amdgcn_cvt_pkrtz(gelu_f(v[0]), gelu_f(v[1]));
                half2_t g23 = __builtin_amdgcn_cvt_pkrtz(gelu_f(v[2]), gelu_f(v[3]));
                half4 h;
                h[0] = g01[0]; h[1] = g01[1]; h[2] = g23[0]; h[3] = g23[1];
                *(half4*)&act[s][(pt ? eb1 : eb0) + cx] = h;
            }
        }
    };

    auto K3 = [&](int s, floatx4& af){
        if (wv < 2){
            floatx4 a = (floatx4){0.f,0.f,0.f,0.f};
            int pb = (wv*16 + ln15)*256 + qx8;
            #pragma unroll
            for (int ks = 0; ks < 8; ks++)
                a = mfma16(wp3[ks*64 + lane],
                           *(const half8*)&act[s][pb + ((ks << 5) ^ kb32)], a);
            af = a;
        }
    };

    auto OUTSIG = [&](int s, floatx4 af){
        if (wv < 2 && quad == 0){
            #pragma unroll
            for (int r = 0; r < 3; r++)
                w0s[s*96 + r*32 + wv*16 + ln15] = sigmoid_f(af[r] + b3v[r]);
        }
    };

    auto STORE = [&](int s){
        if (tid < 24){
            int c = tid >> 3, i = tid & 7;
            float4* dst = (float4*)(out + (b*3 + c)*HW + hw0 + s*32);
            dst[i] = ((float4*)(w0s + s*96 + c*32))[i];
        }
    };

    // ---------------- pipelined schedule ----------------
    L0(0);                         __syncthreads();   // S1
    KL(0, wp1, b1v, accA); L0(1);  __syncthreads();   // S2: MFMA(A) + VALU(B)
    EP(0, accA); KL(1, wp1, b1v, accB); __syncthreads(); // S3
    KL(0, wp2, b2v, accA); EP(1, accB); __syncthreads(); // S4
    EP(0, accA); KL(1, wp2, b2v, accB); __syncthreads(); // S5
    K3(0, accfA); EP(1, accB);     __syncthreads();   // S6
    OUTSIG(0, accfA); K3(1, accfB); __syncthreads();  // S7
    STORE(0); OUTSIG(1, accfB);    __syncthreads();   // S8
    STORE(1);                                          // S9
}

extern "C" void kernel_launch(void* const* d_in, const int* in_sizes, int n_in,
                              void* d_out, int out_size, void* d_ws, size_t ws_size,
                              hipStream_t stream){
    const float* rgb = (const float*)d_in[0];
    const int*  sidx = (const int*) d_in[1];
    const float* emb = (const float*)d_in[2];
    const float* W0  = (const float*)d_in[3];
    const float* b0  = (const float*)d_in[4];
    const float* W1  = (const float*)d_in[5];
    const float* b1  = (const float*)d_in[6];
    const float* W2  = (const float*)d_in[7];
    const float* b2  = (const float*)d_in[8];
    const float* W3  = (const float*)d_in[9];
    const float* b3  = (const float*)d_in[10];
    float* out = (float*)d_out;

    _Float16* wp = (_Float16*)d_ws;                    // 135168 f16 = 270336 B
    float*    c0 = (float*)((char*)d_ws + 270336);     // 512 f32

    int n_pix = in_sizes[0] / 3;                       // 524288
    prep_all<<<82, 256, 0, stream>>>(W1, W2, W3, emb, sidx, W0, b0, wp, c0);
    nilut_main<<<n_pix / 64, 256, 0, stream>>>(rgb, W0, b1, b2, b3, wp, c0, out);
}

// Round 11
// 281.760 us; speedup vs baseline: 1.0817x; 1.0817x over previous
//
#include <hip/hip_runtime.h>

#define HW  (512*512)

typedef _Float16 half8  __attribute__((__vector_size__(16)));
typedef _Float16 half4  __attribute__((__vector_size__(8)));
typedef _Float16 half2_t __attribute__((__vector_size__(4)));
typedef float    floatx4 __attribute__((__vector_size__(16)));

__device__ __forceinline__ float gelu_f(float x){
    float x2 = x * x;
    float q  = __builtin_fmaf(x2, -0.1029432f, -2.3022079f);
    float e  = __builtin_amdgcn_exp2f(x * q);
    return x * __builtin_amdgcn_rcpf(1.0f + e);
}

__device__ __forceinline__ float sigmoid_f(float x){
    float e = __builtin_amdgcn_exp2f(-1.44269504f * x);
    return __builtin_amdgcn_rcpf(1.0f + e);
}

// act layout: element (px, n) at f16 offset px*256 + ((n>>3) ^ (px&7))*8 + (n&7)
// — proven bank-clean in R9.

// ---------------- prep: coalesced weight pack + per-batch c0 (unchanged R9) ----
__global__ void prep_all(const float* __restrict__ W1, const float* __restrict__ W2,
                         const float* __restrict__ W3, const float* __restrict__ emb,
                         const int* __restrict__ sidx, const float* __restrict__ W0,
                         const float* __restrict__ b0,
                         _Float16* __restrict__ wp, float* __restrict__ c0){
    __shared__ float ld[32][68];
    int blk = blockIdx.x;
    int tid = threadIdx.x;
    if (blk < 64){
        int mat = blk >> 5;
        int g   = blk & 31;
        int ks  = g >> 2;
        int ntq = g & 3;
        const float* W = mat ? W2 : W1;
        int row = tid >> 3;
        int c8  = (tid & 7) * 8;
        const float* src = &W[(ks*32 + row)*256 + ntq*64 + c8];
        *(floatx4*)&ld[row][c8]     = *(const floatx4*)src;
        *(floatx4*)&ld[row][c8 + 4] = *(const floatx4*)(src + 4);
        __syncthreads();
        int lane = tid & 63;
        int nt_l = tid >> 6;
        half8 h;
        #pragma unroll
        for (int j = 0; j < 8; j++)
            h[j] = (_Float16)ld[(lane >> 4)*8 + j][nt_l*16 + (lane & 15)];
        _Float16* dst = wp + mat*65536 + (ks*16 + ntq*4 + nt_l)*512 + lane*8;
        *(half8*)dst = h;
    } else if (blk < 80){
        int i    = (blk - 64)*256 + tid;
        int j    = i & 7;
        int lane = (i >> 3) & 63;
        int ks   = i >> 9;
        int k = ks*32 + ((lane >> 4) << 3) + j;
        int n = lane & 15;
        wp[131072 + i] = (_Float16)((n < 3) ? W3[k*3 + n] : 0.0f);
    } else {
        int b = blk - 80;
        int s = sidx[b];
        float acc = b0[tid];
        #pragma unroll 8
        for (int d = 0; d < 64; d++)
            acc = fmaf(emb[s*64 + d], W0[(3 + d)*256 + tid], acc);
        c0[b*256 + tid] = acc;
    }
}

__device__ __forceinline__ floatx4 mfma16(half8 a, half8 b, floatx4 c){
    return __builtin_amdgcn_mfma_f32_16x16x32_f16(a, b, c, 0, 0, 0);
}

// ---------------- fused MLP: 64-px tile, 256 threads, LDS = act only (32 KB) ----
// 5 blocks/CU (5 x 32768 B = 160 KiB exactly) + reg cap 102 -> 20 waves/CU.
__global__ __launch_bounds__(256, 5)
void nilut_main(const float* __restrict__ rgb,
                const float* __restrict__ W0,
                const float* __restrict__ b1v,
                const float* __restrict__ b2v,
                const float* __restrict__ b3v,
                const _Float16* __restrict__ wp,
                const float* __restrict__ c0,
                float* __restrict__ out){
    __shared__ __align__(16) _Float16 act[64 * 256];    // 32768 B — the ONLY LDS
    float* actf = (float*)act;

    const int tid = threadIdx.x;
    const int wg  = blockIdx.x;
    const int pixbase = wg * 64;
    const int b   = pixbase >> 18;
    const int hw0 = pixbase & (HW - 1);

    // ---- stage W0[0:3] + c0[b] into act (as float), consumed into regs below ----
    #pragma unroll
    for (int r = 0; r < 4; r++){
        int q = r*256 + tid;
        actf[q] = (q < 768) ? W0[q] : c0[b*256 + (q - 768)];
    }
    __syncthreads();

    const int ng = tid & 31, rg = tid >> 5;
    floatx4 cw[4][2];
    #pragma unroll
    for (int p = 0; p < 4; p++){
        cw[p][0] = *(const floatx4*)&actf[p*256 + ng*8];
        cw[p][1] = *(const floatx4*)&actf[p*256 + ng*8 + 4];
    }
    __syncthreads();   // all cw reads complete before act is overwritten

    // ---- layer 0: coeffs in regs, rgb direct from global (L1 broadcast) ----
    #pragma unroll
    for (int hf = 0; hf < 2; hf++){
        floatx4 rv[3];
        #pragma unroll
        for (int c = 0; c < 3; c++)
            rv[c] = *(const floatx4*)&rgb[b*3*HW + c*HW + hw0 + rg*8 + hf*4];
        #pragma unroll
        for (int r4 = 0; r4 < 4; r4++){
            int px = rg*8 + hf*4 + r4;
            float rr = rv[0][r4], gg = rv[1][r4], bb = rv[2][r4];
            half8 v;
            #pragma unroll
            for (int j = 0; j < 8; j++){
                int hi = j >> 2, lo = j & 3;
                float z = fmaf(rr, cw[0][hi][lo],
                          fmaf(gg, cw[1][hi][lo],
                          fmaf(bb, cw[2][hi][lo], cw[3][hi][lo])));
                v[j] = (_Float16)gelu_f(z);
            }
            *(half8*)&act[px*256 + ((ng ^ (px & 7)) << 3)] = v;
        }
    }
    __syncthreads();

    const int lane = tid & 63;
    const int wv   = tid >> 6;
    const int ln15 = lane & 15;
    const int quad = lane >> 4;
    const int qr   = quad * 4;
    const int sx   = ln15 & 7;
    const int qx8  = (quad ^ (sx & 3)) * 8;
    const int kb32 = ((sx >> 2) & 1) << 5;
    const int qh   = quad >> 1, qs = (quad & 1) * 4;

    int pbq[4], eb[4];
    #pragma unroll
    for (int pt = 0; pt < 4; pt++){
        pbq[pt] = (pt*16 + ln15)*256 + qx8;
        eb[pt]  = (pt*16 + ln15)*256 + qs;
    }

    // ---- layers 1 and 2: D = W(A) x act(B), wave wv owns n_out tiles wv*4..+3 ----
    const _Float16* wl  = wp;
    const float* bias   = b1v;
    #pragma unroll 1
    for (int L = 0; L < 2; L++){
        floatx4 acc[4][4];                // [pt][mtl]
        #pragma unroll
        for (int mtl = 0; mtl < 4; mtl++){
            floatx4 bv = *(const floatx4*)&bias[(wv*4 + mtl)*16 + qr];
            #pragma unroll
            for (int pt = 0; pt < 4; pt++)
                acc[pt][mtl] = bv;
        }

        const half8* wp8 = (const half8*)wl;
        #pragma unroll 2
        for (int ks = 0; ks < 8; ks++){
            int t = (ks << 5) ^ kb32;
            half8 bfr[4];
            #pragma unroll
            for (int pt = 0; pt < 4; pt++)
                bfr[pt] = *(const half8*)&act[pbq[pt] + t];
            #pragma unroll
            for (int mtl = 0; mtl < 4; mtl++){
                half8 af = wp8[(ks*16 + wv*4 + mtl)*64 + lane];
                #pragma unroll
                for (int pt = 0; pt < 4; pt++)
                    acc[pt][mtl] = mfma16(af, bfr[pt], acc[pt][mtl]);
            }
        }
        __syncthreads();   // all reads of act done before overwrite
        #pragma unroll
        for (int mtl = 0; mtl < 4; mtl++){
            int cx = (((wv*4 + mtl)*2 + qh) ^ sx) << 3;
            #pragma unroll
            for (int pt = 0; pt < 4; pt++){
                floatx4 v = acc[pt][mtl];
                half2_t g01 = __builtin_amdgcn_cvt_pkrtz(gelu_f(v[0]), gelu_f(v[1]));
                half2_t g23 = __builtin_amdgcn_cvt_pkrtz(gelu_f(v[2]), gelu_f(v[3]));
                half4 h;
                h[0] = g01[0]; h[1] = g01[1]; h[2] = g23[0]; h[3] = g23[1];
                *(half4*)&act[eb[pt] + cx] = h;
            }
        }
        __syncthreads();
        wl = wp + 65536;
        bias = b2v;
    }

    // ---- final layer 256 -> 3 (padded to 16) + sigmoid ----
    {
        const half8* wp8 = (const half8*)(wp + 131072);
        floatx4 ac = (floatx4){0.f,0.f,0.f,0.f};
        int pb = (wv*16 + ln15)*256 + qx8;
        #pragma unroll
        for (int ks = 0; ks < 8; ks++){
            half8 bfr = *(const half8*)&act[pb + ((ks << 5) ^ kb32)];
            half8 af  = wp8[ks*64 + lane];
            ac = mfma16(af, bfr, ac);
        }
        __syncthreads();   // act reads done before bounce overwrites act
        // bounce [3][64] floats into dead act space
        if (quad == 0){
            #pragma unroll
            for (int r = 0; r < 3; r++)
                actf[r*64 + wv*16 + ln15] = sigmoid_f(ac[r] + b3v[r]);
        }
        __syncthreads();
        if (tid < 48){
            int c  = tid >> 4;
            int i2 = tid & 15;
            float4* dst = (float4*)(out + (b*3 + c)*HW + hw0);
            dst[i2] = ((float4*)(actf + c*64))[i2];
        }
    }
}

extern "C" void kernel_launch(void* const* d_in, const int* in_sizes, int n_in,
                              void* d_out, int out_size, void* d_ws, size_t ws_size,
                              hipStream_t stream){
    const float* rgb = (const float*)d_in[0];
    const int*  sidx = (const int*) d_in[1];
    const float* emb = (const float*)d_in[2];
    const float* W0  = (const float*)d_in[3];
    const float* b0  = (const float*)d_in[4];
    const float* W1  = (const float*)d_in[5];
    const float* b1  = (const float*)d_in[6];
    const float* W2  = (const float*)d_in[7];
    const float* b2  = (const float*)d_in[8];
    const float* W3  = (const float*)d_in[9];
    const float* b3  = (const float*)d_in[10];
    float* out = (float*)d_out;

    _Float16* wp = (_Float16*)d_ws;                    // 135168 f16 = 270336 B
    float*    c0 = (float*)((char*)d_ws + 270336);     // 512 f32

    int n_pix = in_sizes[0] / 3;                       // 524288
    prep_all<<<82, 256, 0, stream>>>(W1, W2, W3, emb, sidx, W0, b0, wp, c0);
    nilut_main<<<n_pix / 64, 256, 0, stream>>>(rgb, W0, b1, b2, b3, wp, c0, out);
}